// Round 1
// baseline (1561.956 us; speedup 1.0000x reference)
//
#include <hip/hip_runtime.h>
#include <math.h>

#define NN 1395
#define EE 44640

// ---------------- workspace layout (float offsets) ----------------
// zero-region (memset each call): agg1, agg2, y1, y2
//   agg1 : 0      .. 44640   (N*32)  -> becomes h1 in place
//   agg2 : 44640  .. 86490   (N*30)  -> becomes h2 in place
//   y1   : 86496  .. 87520   (1024)
//   y2   : 87520  .. 88544   (1024)
// non-zeroed (fully overwritten each call):
//   deg  : 88544  .. 89939   (N)     -> becomes dinv in place
//   h1p  : 89952  .. 134592  (N*32)
//   h2p  : 134592 .. 176442  (N*30)
//   h3   : 176448 .. 444288  (N*192)
//   h4   : 444288 .. 712128  (N*192)
//   h5   : 712128 .. 979968  (N*192)
// total ~3.92 MB

static __global__ void k_deg_init(float* __restrict__ deg) {
  int i = blockIdx.x * blockDim.x + threadIdx.x;
  if (i < NN) deg[i] = 1.0f;  // self loop
}

static __global__ void k_deg_edges(const int* __restrict__ ei, float* __restrict__ deg) {
  int e = blockIdx.x * blockDim.x + threadIdx.x;
  if (e < EE) atomicAdd(&deg[ei[EE + e]], 1.0f);  // dst = row 1
}

static __global__ void k_dinv(float* __restrict__ deg) {
  int i = blockIdx.x * blockDim.x + threadIdx.x;
  if (i < NN) deg[i] = rsqrtf(deg[i]);
}

// h1p = x @ w1, with x[:, :3] zeroed (so only features 3..5 contribute)
static __global__ void k_xw1(const float* __restrict__ x, const float* __restrict__ w1,
                             float* __restrict__ h1p) {
  int idx = blockIdx.x * blockDim.x + threadIdx.x;
  if (idx >= NN * 32) return;
  int i = idx >> 5, j = idx & 31;
  float s = 0.f;
  s += x[i * 6 + 3] * w1[3 * 32 + j];
  s += x[i * 6 + 4] * w1[4 * 32 + j];
  s += x[i * 6 + 5] * w1[5 * 32 + j];
  h1p[idx] = s;
}

// agg[dst] += dinv[src]*dinv[dst] * hp[src]  over E edges (atomics)
template <int C>
static __global__ void k_prop(const int* __restrict__ ei, const float* __restrict__ dinv,
                              const float* __restrict__ hp, float* __restrict__ agg) {
  int idx = blockIdx.x * blockDim.x + threadIdx.x;
  if (idx >= EE * C) return;
  int e = idx / C, c = idx - e * C;
  int s = ei[e], d = ei[EE + e];
  float coef = dinv[s] * dinv[d];
  atomicAdd(&agg[d * C + c], coef * hp[s * C + c]);
}

// h = leaky(agg + dinv[i]^2 * hp + b)   (self-loop term + bias + LeakyReLU, in place)
template <int C>
static __global__ void k_finalize(const float* __restrict__ dinv, const float* __restrict__ hp,
                                  const float* __restrict__ b, float* __restrict__ agg) {
  int idx = blockIdx.x * blockDim.x + threadIdx.x;
  if (idx >= NN * C) return;
  int i = idx / C, c = idx - i * C;
  float di = dinv[i];
  float v = agg[idx] + di * di * hp[idx] + b[c];
  agg[idx] = v > 0.f ? v : 0.2f * v;
}

// out[N,COUT] = h[N,K] @ W[K,COUT]   (no bias; for gcn2 transform)
template <int K, int COUT>
static __global__ void k_dense_small(const float* __restrict__ h, const float* __restrict__ W,
                                     float* __restrict__ out) {
  int idx = blockIdx.x * blockDim.x + threadIdx.x;
  if (idx >= NN * COUT) return;
  int i = idx / COUT, j = idx - i * COUT;
  float s = 0.f;
#pragma unroll
  for (int k = 0; k < K; ++k) s += h[i * K + k] * W[k * COUT + j];
  out[idx] = s;
}

// per-node linear to 192 channels: block = node, 192 threads, row in LDS,
// W reads coalesced across j.
template <int K>
static __global__ void k_nodelinear(const float* __restrict__ h, const float* __restrict__ W,
                                    const float* __restrict__ b, float* __restrict__ out) {
  __shared__ float lds[K];
  int i = blockIdx.x;
  int j = threadIdx.x;  // 0..191
  for (int k = j; k < K; k += 192) lds[k] = h[i * K + k];
  __syncthreads();
  float s = b[j];
#pragma unroll 6
  for (int k = 0; k < K; ++k) s += lds[k] * W[k * 192 + j];
  out[i * 192 + j] = s;
}

// ---- fc1: y1[1024] += v[267840] @ fw1[267840,1024], split-K over blocks ----
#define FC1_K 267840
#define FC1_RPB 262
#define FC1_NB 1023  // 1023*262 = 268026 >= 267840

static __global__ void k_fc1(const float* __restrict__ v, const float* __restrict__ W,
                             float* __restrict__ y) {
  int t = threadIdx.x;  // 256 threads, 4 cols each
  int k0 = blockIdx.x * FC1_RPB;
  int k1 = k0 + FC1_RPB;
  if (k1 > FC1_K) k1 = FC1_K;
  const float4* __restrict__ W4 = (const float4*)W;
  float4 acc = make_float4(0.f, 0.f, 0.f, 0.f);
  for (int k = k0; k < k1; ++k) {
    float vk = v[k];
    float4 w = W4[(size_t)k * 256 + t];
    acc.x += vk * w.x;
    acc.y += vk * w.y;
    acc.z += vk * w.z;
    acc.w += vk * w.w;
  }
  atomicAdd(&y[4 * t + 0], acc.x);
  atomicAdd(&y[4 * t + 1], acc.y);
  atomicAdd(&y[4 * t + 2], acc.z);
  atomicAdd(&y[4 * t + 3], acc.w);
}

// ---- fc2: y2[1024] += (y1+fb1) @ fw2[1024,1024] ----
static __global__ void k_fc2(const float* __restrict__ y1, const float* __restrict__ fb1,
                             const float* __restrict__ W, float* __restrict__ y2) {
  int t = threadIdx.x;  // 256 threads, 4 cols each; 64 blocks x 16 rows
  int k0 = blockIdx.x * 16;
  const float4* __restrict__ W4 = (const float4*)W;
  float4 acc = make_float4(0.f, 0.f, 0.f, 0.f);
  for (int k = k0; k < k0 + 16; ++k) {
    float vk = y1[k] + fb1[k];
    float4 w = W4[(size_t)k * 256 + t];
    acc.x += vk * w.x;
    acc.y += vk * w.y;
    acc.z += vk * w.z;
    acc.w += vk * w.w;
  }
  atomicAdd(&y2[4 * t + 0], acc.x);
  atomicAdd(&y2[4 * t + 1], acc.y);
  atomicAdd(&y2[4 * t + 2], acc.z);
  atomicAdd(&y2[4 * t + 3], acc.w);
}

// ---- fc3 + group-of-4 L2 normalize, single block ----
static __global__ void k_fc3_norm(const float* __restrict__ y2, const float* __restrict__ fb2,
                                  const float* __restrict__ W, const float* __restrict__ fb3,
                                  float* __restrict__ out) {
  __shared__ float v[1024];
  __shared__ float partial[4][64];
  __shared__ float res[64];
  int t = threadIdx.x;  // 256
  for (int k = t; k < 1024; k += 256) v[k] = y2[k] + fb2[k];
  __syncthreads();
  int j = t & 63, p = t >> 6;
  float s = 0.f;
  int k0 = p * 256;
  for (int k = k0; k < k0 + 256; ++k) s += v[k] * W[k * 64 + j];
  partial[p][j] = s;
  __syncthreads();
  if (t < 64) res[t] = partial[0][t] + partial[1][t] + partial[2][t] + partial[3][t] + fb3[t];
  __syncthreads();
  if (t < 64) {
    int g = t & ~3;
    float m = rsqrtf(res[g] * res[g] + res[g + 1] * res[g + 1] +
                     res[g + 2] * res[g + 2] + res[g + 3] * res[g + 3]);
    out[t] = res[t] * m;
  }
}

extern "C" void kernel_launch(void* const* d_in, const int* in_sizes, int n_in,
                              void* d_out, int out_size, void* d_ws, size_t ws_size,
                              hipStream_t stream) {
  const float* x   = (const float*)d_in[0];
  const int*   ei  = (const int*)d_in[1];
  const float* w1  = (const float*)d_in[2];
  const float* b1  = (const float*)d_in[3];
  const float* w2  = (const float*)d_in[4];
  const float* b2  = (const float*)d_in[5];
  const float* qw1 = (const float*)d_in[6];
  const float* qb1 = (const float*)d_in[7];
  const float* qw2 = (const float*)d_in[8];
  const float* qb2 = (const float*)d_in[9];
  const float* qw3 = (const float*)d_in[10];
  const float* qb3 = (const float*)d_in[11];
  const float* fw1 = (const float*)d_in[12];
  const float* fb1 = (const float*)d_in[13];
  const float* fw2 = (const float*)d_in[14];
  const float* fb2 = (const float*)d_in[15];
  const float* fw3 = (const float*)d_in[16];
  const float* fb3 = (const float*)d_in[17];
  float* out = (float*)d_out;
  float* ws  = (float*)d_ws;

  float* agg1 = ws + 0;
  float* agg2 = ws + 44640;
  float* y1   = ws + 86496;
  float* y2   = ws + 87520;
  float* deg  = ws + 88544;  // becomes dinv
  float* h1p  = ws + 89952;
  float* h2p  = ws + 134592;
  float* h3   = ws + 176448;
  float* h4   = ws + 444288;
  float* h5   = ws + 712128;

  // zero accumulators (ws is poisoned 0xAA before every call)
  hipMemsetAsync(d_ws, 0, 88544 * sizeof(float), stream);

  k_deg_init<<<(NN + 255) / 256, 256, 0, stream>>>(deg);
  k_deg_edges<<<(EE + 255) / 256, 256, 0, stream>>>(ei, deg);
  k_dinv<<<(NN + 255) / 256, 256, 0, stream>>>(deg);

  k_xw1<<<(NN * 32 + 255) / 256, 256, 0, stream>>>(x, w1, h1p);
  k_prop<32><<<(EE * 32 + 255) / 256, 256, 0, stream>>>(ei, deg, h1p, agg1);
  k_finalize<32><<<(NN * 32 + 255) / 256, 256, 0, stream>>>(deg, h1p, b1, agg1);

  k_dense_small<32, 30><<<(NN * 30 + 255) / 256, 256, 0, stream>>>(agg1, w2, h2p);
  k_prop<30><<<(EE * 30 + 255) / 256, 256, 0, stream>>>(ei, deg, h2p, agg2);
  k_finalize<30><<<(NN * 30 + 255) / 256, 256, 0, stream>>>(deg, h2p, b2, agg2);

  k_nodelinear<30><<<NN, 192, 0, stream>>>(agg2, qw1, qb1, h3);
  k_nodelinear<192><<<NN, 192, 0, stream>>>(h3, qw2, qb2, h4);
  k_nodelinear<192><<<NN, 192, 0, stream>>>(h4, qw3, qb3, h5);

  k_fc1<<<FC1_NB, 256, 0, stream>>>(h5, fw1, y1);
  k_fc2<<<64, 256, 0, stream>>>(y1, fb1, fw2, y2);
  k_fc3_norm<<<1, 256, 0, stream>>>(y2, fb2, fw3, fb3, out);
}